// Round 5
// baseline (1035.754 us; speedup 1.0000x reference)
//
#include <hip/hip_runtime.h>
#include <hip/hip_bf16.h>
#include <math.h>

#define NNODES 4096

// ---------------------------------------------------------------------------
// Dtype probe: flag[0]=1 => inputs fp32, 0 => bf16.
// bf16 data: low half of each word is a sane bf16 (exp ~[0x69,0x7F]) -> ~0 insane.
// fp32 data: low 16 bits are mantissa noise -> ~44% of lanes insane.
// ---------------------------------------------------------------------------
__global__ void probe_dtype(const unsigned int* __restrict__ aw, int* __restrict__ flag) {
    int tid = threadIdx.x;                 // 64 threads
    unsigned w = aw[tid];
    unsigned e = (w >> 7) & 0xffu;
    bool insane = (e >= 0xC0u) || (e <= 0x30u);
    unsigned long long m = __ballot(insane);
    if (tid == 0) flag[0] = (__popcll(m) >= 16) ? 1 : 0;
}

__device__ __forceinline__ float ldf(const void* p, size_t i, int isf32) {
    return isf32 ? ((const float*)p)[i]
                 : __bfloat162float(((const __hip_bfloat16*)p)[i]);
}

__device__ __forceinline__ void ld8(float* d, const void* p, size_t e, int isf32) {
    if (isf32) {
        const float4* s = (const float4*)((const float*)p + e);
        float4 f0 = s[0], f1 = s[1];
        d[0] = f0.x; d[1] = f0.y; d[2] = f0.z; d[3] = f0.w;
        d[4] = f1.x; d[5] = f1.y; d[6] = f1.z; d[7] = f1.w;
    } else {
        const __hip_bfloat16* s = (const __hip_bfloat16*)p + e;
#pragma unroll
        for (int j = 0; j < 8; j++) d[j] = __bfloat162float(s[j]);
    }
}

// ---------------------------------------------------------------------------
// Kernel A: thread per (k, b, n). y[k][b][t][n] = sum_m adj[k][n][m]*x[b][t][m]
// Stored as yws[(b*4096+n)*36 + k*12 + t] for contiguous epilogue reads.
// ---------------------------------------------------------------------------
__global__ __launch_bounds__(64) void hop_kernel(
    const void* __restrict__ xv, const void* __restrict__ adjv,
    float* __restrict__ yws, const int* __restrict__ flag)
{
    const int g = blockIdx.x * 64 + threadIdx.x;   // 0..98303
    const int k = g >> 15;
    const int r = g & 32767;
    const int b = r >> 12;
    const int n = r & (NNODES - 1);
    const int isf32 = flag[0];

    float acc[12];
#pragma unroll
    for (int t = 0; t < 12; t++) acc[t] = 0.f;

    const size_t arow = ((size_t)(k * NNODES + n)) * NNODES;
    for (int m0 = 0; m0 < NNODES; m0 += 8) {
        float a8[8];
        ld8(a8, adjv, arow + m0, isf32);
#pragma unroll
        for (int t = 0; t < 12; t++) {
            float x8[8];
            ld8(x8, xv, ((size_t)(b * 12 + t)) * NNODES + m0, isf32);
#pragma unroll
            for (int j = 0; j < 8; j++) acc[t] += a8[j] * x8[j];
        }
    }
#pragma unroll
    for (int t = 0; t < 12; t++)
        yws[(size_t)r * 36 + k * 12 + t] = acc[t];
}

// ---------------------------------------------------------------------------
// Kernel B: epilogue, thread per (b, n). Reads y[36] contiguous from ws.
// ---------------------------------------------------------------------------
__global__ __launch_bounds__(64) void epilogue_kernel(
    const void* __restrict__ xv, const float* __restrict__ yws,
    const void* __restrict__ chebv, const void* __restrict__ gcnwv,
    const void* __restrict__ gcnbv, const void* __restrict__ g1wv,
    const void* __restrict__ g1bv, const void* __restrict__ g2wv,
    const void* __restrict__ g2bv,
    float* __restrict__ out, const int* __restrict__ flag)
{
    __shared__ float gwL[9216];   // [t][j*12+o]
    __shared__ float cwL[192];    // [j*3+k]
    __shared__ float w1L[216];    // [o*18 + c*3 + kh]  (kw=1 tap)
    __shared__ float w2L[216];
    __shared__ float wbL[36];

    const int tid = threadIdx.x;
    const int isf32 = flag[0];

    for (int i = tid; i < 9216; i += 64) {
        int o = i / 768, t = (i / 64) % 12, j = i % 64;   // gcn_w flat (o,t,0,j)
        gwL[t * 768 + j * 12 + o] = ldf(gcnwv, i, isf32);
    }
    for (int i = tid; i < 192; i += 64) cwL[i] = ldf(chebv, i, isf32);
    for (int i = tid; i < 216; i += 64) {
        w1L[i] = ldf(g1wv, (size_t)i * 3 + 1, isf32);
        w2L[i] = ldf(g2wv, (size_t)i * 3 + 1, isf32);
    }
    if (tid < 12) {
        wbL[tid]      = ldf(gcnbv, tid, isf32);
        wbL[12 + tid] = ldf(g1bv, tid, isf32);
        wbL[24 + tid] = ldf(g2bv, tid, isf32);
    }
    __syncthreads();

    const int g = blockIdx.x * 64 + tid;   // 0..32767
    const int b = g >> 12;
    const int n = g & (NNODES - 1);

    float y[36];
#pragma unroll
    for (int i = 0; i < 36; i++) y[i] = yws[(size_t)g * 36 + i];

    // ---- cheb -> relu -> sgc ----
    float sg[12];
#pragma unroll
    for (int o = 0; o < 12; o++) sg[o] = wbL[o];
    for (int t = 0; t < 12; t++) {
        const float y0 = y[t], y1 = y[12 + t], y2 = y[24 + t];
        const float* gwt = gwL + t * 768;
#pragma unroll 4
        for (int j = 0; j < 64; j++) {
            float h = y0 * cwL[j * 3] + y1 * cwL[j * 3 + 1] + y2 * cwL[j * 3 + 2];
            h = fmaxf(h, 0.f);
#pragma unroll
            for (int o = 0; o < 12; o++) sg[o] += h * gwt[j * 12 + o];
        }
    }

    // ---- GLU (dilated conv: taps n-2, n, n+2; only kw=1 alive) ----
    float xa[18], xg[18];
#pragma unroll
    for (int c = 0; c < 6; c++)
#pragma unroll
        for (int kh = 0; kh < 3; kh++) {
            int m = n + 2 * kh - 2;
            bool ok = ((unsigned)m < (unsigned)NNODES);
            xa[c * 3 + kh] = ok ? ldf(xv, ((size_t)(b * 12 + c)) * NNODES + m, isf32) : 0.f;
            xg[c * 3 + kh] = ok ? ldf(xv, ((size_t)(b * 12 + c + 6)) * NNODES + m, isf32) : 0.f;
        }

#pragma unroll
    for (int o = 0; o < 12; o++) {
        float av = wbL[12 + o], gv = wbL[24 + o];
#pragma unroll
        for (int i = 0; i < 18; i++) {
            av += xa[i] * w1L[o * 18 + i];
            gv += xg[i] * w2L[o * 18 + i];
        }
        float s = 1.f / (1.f + expf(-gv));
        out[((size_t)(b * 12 + o)) * NNODES + n] = av * s + sg[o];
    }
}

// ---------------------------------------------------------------------------
// Fallback single kernel (used only if ws too small for y staging):
// identical math, thread per (b,n), fp32 out.
// ---------------------------------------------------------------------------
__global__ __launch_bounds__(64) void fused_simple(
    const void* __restrict__ xv, const void* __restrict__ adjv,
    const void* __restrict__ chebv, const void* __restrict__ gcnwv,
    const void* __restrict__ gcnbv, const void* __restrict__ g1wv,
    const void* __restrict__ g1bv, const void* __restrict__ g2wv,
    const void* __restrict__ g2bv,
    float* __restrict__ out, const int* __restrict__ flag)
{
    __shared__ float gwL[9216];
    __shared__ float cwL[192];
    __shared__ float w1L[216];
    __shared__ float w2L[216];
    __shared__ float wbL[36];

    const int tid = threadIdx.x;
    const int isf32 = flag[0];

    for (int i = tid; i < 9216; i += 64) {
        int o = i / 768, t = (i / 64) % 12, j = i % 64;
        gwL[t * 768 + j * 12 + o] = ldf(gcnwv, i, isf32);
    }
    for (int i = tid; i < 192; i += 64) cwL[i] = ldf(chebv, i, isf32);
    for (int i = tid; i < 216; i += 64) {
        w1L[i] = ldf(g1wv, (size_t)i * 3 + 1, isf32);
        w2L[i] = ldf(g2wv, (size_t)i * 3 + 1, isf32);
    }
    if (tid < 12) {
        wbL[tid]      = ldf(gcnbv, tid, isf32);
        wbL[12 + tid] = ldf(g1bv, tid, isf32);
        wbL[24 + tid] = ldf(g2bv, tid, isf32);
    }
    __syncthreads();

    const int g = blockIdx.x * 64 + tid;
    const int b = g >> 12;
    const int n = g & (NNODES - 1);

    float y[3][12];
#pragma unroll
    for (int k = 0; k < 3; k++)
#pragma unroll
        for (int t = 0; t < 12; t++) y[k][t] = 0.f;

    for (int m0 = 0; m0 < NNODES; m0 += 8) {
        float a0[8], a1[8], a2[8];
        ld8(a0, adjv, ((size_t)(0 * NNODES + n)) * NNODES + m0, isf32);
        ld8(a1, adjv, ((size_t)(1 * NNODES + n)) * NNODES + m0, isf32);
        ld8(a2, adjv, ((size_t)(2 * NNODES + n)) * NNODES + m0, isf32);
#pragma unroll
        for (int t = 0; t < 12; t++) {
            float x8[8];
            ld8(x8, xv, ((size_t)(b * 12 + t)) * NNODES + m0, isf32);
#pragma unroll
            for (int j = 0; j < 8; j++) {
                y[0][t] += a0[j] * x8[j];
                y[1][t] += a1[j] * x8[j];
                y[2][t] += a2[j] * x8[j];
            }
        }
    }

    float sg[12];
#pragma unroll
    for (int o = 0; o < 12; o++) sg[o] = wbL[o];
    for (int t = 0; t < 12; t++) {
        const float y0 = y[0][t], y1 = y[1][t], y2 = y[2][t];
        const float* gwt = gwL + t * 768;
#pragma unroll 4
        for (int j = 0; j < 64; j++) {
            float h = y0 * cwL[j * 3] + y1 * cwL[j * 3 + 1] + y2 * cwL[j * 3 + 2];
            h = fmaxf(h, 0.f);
#pragma unroll
            for (int o = 0; o < 12; o++) sg[o] += h * gwt[j * 12 + o];
        }
    }

    float xa[18], xg[18];
#pragma unroll
    for (int c = 0; c < 6; c++)
#pragma unroll
        for (int kh = 0; kh < 3; kh++) {
            int m = n + 2 * kh - 2;
            bool ok = ((unsigned)m < (unsigned)NNODES);
            xa[c * 3 + kh] = ok ? ldf(xv, ((size_t)(b * 12 + c)) * NNODES + m, isf32) : 0.f;
            xg[c * 3 + kh] = ok ? ldf(xv, ((size_t)(b * 12 + c + 6)) * NNODES + m, isf32) : 0.f;
        }

#pragma unroll
    for (int o = 0; o < 12; o++) {
        float av = wbL[12 + o], gv = wbL[24 + o];
#pragma unroll
        for (int i = 0; i < 18; i++) {
            av += xa[i] * w1L[o * 18 + i];
            gv += xg[i] * w2L[o * 18 + i];
        }
        float s = 1.f / (1.f + expf(-gv));
        out[((size_t)(b * 12 + o)) * NNODES + n] = av * s + sg[o];
    }
}

// ---------------------------------------------------------------------------
extern "C" void kernel_launch(void* const* d_in, const int* in_sizes, int n_in,
                              void* d_out, int out_size, void* d_ws, size_t ws_size,
                              hipStream_t stream)
{
    int* flag = (int*)d_ws;                       // 64 B reserved
    float* yws = (float*)((char*)d_ws + 64);      // 32768*36 floats = 4.72 MB
    const size_t need = 64 + (size_t)32768 * 36 * 4;

    hipLaunchKernelGGL(probe_dtype, dim3(1), dim3(64), 0, stream,
                       (const unsigned int*)d_in[1], flag);

    if (ws_size >= need) {
        hipLaunchKernelGGL(hop_kernel, dim3(1536), dim3(64), 0, stream,
                           d_in[0], d_in[1], yws, flag);
        hipLaunchKernelGGL(epilogue_kernel, dim3(512), dim3(64), 0, stream,
                           d_in[0], yws, d_in[2], d_in[3], d_in[4],
                           d_in[5], d_in[6], d_in[7], d_in[8],
                           (float*)d_out, flag);
    } else {
        hipLaunchKernelGGL(fused_simple, dim3(512), dim3(64), 0, stream,
                           d_in[0], d_in[1], d_in[2], d_in[3], d_in[4],
                           d_in[5], d_in[6], d_in[7], d_in[8],
                           (float*)d_out, flag);
    }
}

// Round 6
// 418.279 us; speedup vs baseline: 2.4762x; 2.4762x over previous
//
#include <hip/hip_runtime.h>
#include <hip/hip_bf16.h>
#include <math.h>

#define NNODES 4096
#define NCOLS  96          // B*T
#define NROWS  12288       // K*NNODES

typedef __attribute__((ext_vector_type(8))) short short8;
typedef __attribute__((ext_vector_type(4))) float float4v;

// ---------------------------------------------------------------------------
// Dtype probe: flag[0]=1 => inputs fp32, 0 => bf16. (Validated: fp32 on this
// harness — round 5 passed through the fp32 path.)
// ---------------------------------------------------------------------------
__global__ void probe_dtype(const unsigned int* __restrict__ aw, int* __restrict__ flag) {
    int tid = threadIdx.x;
    unsigned w = aw[tid];
    unsigned e = (w >> 7) & 0xffu;
    bool insane = (e >= 0xC0u) || (e <= 0x30u);
    unsigned long long m = __ballot(insane);
    if (tid == 0) flag[0] = (__popcll(m) >= 16) ? 1 : 0;
}

__device__ __forceinline__ float ldf(const void* p, size_t i, int isf32) {
    return isf32 ? ((const float*)p)[i]
                 : __bfloat162float(((const __hip_bfloat16*)p)[i]);
}

__device__ __forceinline__ void ld8(float* d, const void* p, size_t e, int isf32) {
    if (isf32) {
        const float4* s = (const float4*)((const float*)p + e);
        float4 f0 = s[0], f1 = s[1];
        d[0] = f0.x; d[1] = f0.y; d[2] = f0.z; d[3] = f0.w;
        d[4] = f1.x; d[5] = f1.y; d[6] = f1.z; d[7] = f1.w;
    } else {
        const __hip_bfloat16* s = (const __hip_bfloat16*)p + e;
#pragma unroll
        for (int j = 0; j < 8; j++) d[j] = __bfloat162float(s[j]);
    }
}

// store 4 fp32 as 4 bf16 (8 B, dst must be 8B-aligned)
__device__ __forceinline__ void st4bf(__hip_bfloat16* d, float4 f) {
    __align__(8) __hip_bfloat16 t[4];
    t[0] = __float2bfloat16(f.x); t[1] = __float2bfloat16(f.y);
    t[2] = __float2bfloat16(f.z); t[3] = __float2bfloat16(f.w);
    *(uint2*)d = *(const uint2*)t;
}

// ---------------------------------------------------------------------------
// Kernel 1: y = adj(12288x4096) @ X^T (X = x as 96x4096), bf16 MFMA 16x16x32.
// Grid 192 blocks x 256 thr (4 waves). Tile 64 rows x 96 cols, BK=64.
// fp32 inputs converted to bf16 during staging; register-prefetch pipeline.
// Output: yws[row*96 + col] fp32, row = k*4096+n, col = b*12+t.
// C/D mapping P0 (HW-validated r2/r3): col=lane&15, row=(lane>>4)*4+reg.
// ---------------------------------------------------------------------------
__global__ __launch_bounds__(256) void gemm_y(
    const void* __restrict__ adjv, const void* __restrict__ xv,
    float* __restrict__ yws, const int* __restrict__ flag)
{
    __shared__ __align__(16) __hip_bfloat16 As[64][72];   // +8 pad
    __shared__ __align__(16) __hip_bfloat16 Xs[96][72];

    const int tid = threadIdx.x;
    const int isf32 = flag[0];
    const size_t row0 = (size_t)blockIdx.x * 64;

    const int wv = tid >> 6;
    const int ln = tid & 63;
    const int fr = ln & 15;
    const int fq = ln >> 4;

    float4v acc[6];
#pragma unroll
    for (int i = 0; i < 6; i++) acc[i] = (float4v){0.f, 0.f, 0.f, 0.f};

    if (isf32) {
        const float* adjf = (const float*)adjv;
        const float* xf   = (const float*)xv;
        const int ar = tid >> 2;              // A row 0..63
        const int ac = (tid & 3) * 16;        // A col offset (16 floats)

        float4 ra[4], rx[6];
        // preload chunk 0
#pragma unroll
        for (int i = 0; i < 4; i++)
            ra[i] = *(const float4*)(adjf + (row0 + ar) * NNODES + ac + i * 4);
#pragma unroll
        for (int s = 0; s < 6; s++) {
            int idx = tid + s * 256;                  // 0..1535 float4s
            int r = idx >> 4, c = (idx & 15) * 4;
            rx[s] = *(const float4*)(xf + (size_t)r * NNODES + c);
        }

        for (int kk = 0; kk < NNODES; kk += 64) {
            __syncthreads();                  // prev MFMA done before overwrite
#pragma unroll
            for (int i = 0; i < 4; i++) st4bf(&As[ar][ac + i * 4], ra[i]);
#pragma unroll
            for (int s = 0; s < 6; s++) {
                int idx = tid + s * 256;
                int r = idx >> 4, c = (idx & 15) * 4;
                st4bf(&Xs[r][c], rx[s]);
            }
            if (kk + 64 < NNODES) {
                int kn = kk + 64;
#pragma unroll
                for (int i = 0; i < 4; i++)
                    ra[i] = *(const float4*)(adjf + (row0 + ar) * NNODES + kn + ac + i * 4);
#pragma unroll
                for (int s = 0; s < 6; s++) {
                    int idx = tid + s * 256;
                    int r = idx >> 4, c = (idx & 15) * 4;
                    rx[s] = *(const float4*)(xf + (size_t)r * NNODES + kn + c);
                }
            }
            __syncthreads();
#pragma unroll
            for (int kq = 0; kq < 2; kq++) {
                short8 a = *(const short8*)(&As[wv * 16 + fr][kq * 32 + fq * 8]);
#pragma unroll
                for (int ct = 0; ct < 6; ct++) {
                    short8 b = *(const short8*)(&Xs[ct * 16 + fr][kq * 32 + fq * 8]);
                    acc[ct] = __builtin_amdgcn_mfma_f32_16x16x32_bf16(a, b, acc[ct], 0, 0, 0);
                }
            }
        }
    } else {
        // bf16 input path (insurance; not expected to run): simple staging
        const __hip_bfloat16* adjb = (const __hip_bfloat16*)adjv;
        const __hip_bfloat16* xb   = (const __hip_bfloat16*)xv;
        const int ar = tid >> 2;
        const int ac = (tid & 3) * 16;
        for (int kk = 0; kk < NNODES; kk += 64) {
            __syncthreads();
            *(uint4*)(&As[ar][ac]) =
                *(const uint4*)(adjb + (row0 + ar) * NNODES + kk + ac);
            *(uint4*)(&As[ar][ac + 8]) =
                *(const uint4*)(adjb + (row0 + ar) * NNODES + kk + ac + 8);
#pragma unroll
            for (int s = 0; s < 3; s++) {
                int idx = tid + s * 256;                  // 0..767 chunks of 8
                int r = idx >> 3, c = (idx & 7) * 8;
                *(uint4*)(&Xs[r][c]) =
                    *(const uint4*)(xb + (size_t)r * NNODES + kk + c);
            }
            __syncthreads();
#pragma unroll
            for (int kq = 0; kq < 2; kq++) {
                short8 a = *(const short8*)(&As[wv * 16 + fr][kq * 32 + fq * 8]);
#pragma unroll
                for (int ct = 0; ct < 6; ct++) {
                    short8 b = *(const short8*)(&Xs[ct * 16 + fr][kq * 32 + fq * 8]);
                    acc[ct] = __builtin_amdgcn_mfma_f32_16x16x32_bf16(a, b, acc[ct], 0, 0, 0);
                }
            }
        }
    }

    // store: P0 mapping
#pragma unroll
    for (int ct = 0; ct < 6; ct++)
#pragma unroll
        for (int rg = 0; rg < 4; rg++) {
            size_t r = row0 + wv * 16 + fq * 4 + rg;
            yws[r * NCOLS + ct * 16 + fr] = acc[ct][rg];
        }
}

// ---------------------------------------------------------------------------
// Kernel 2: epilogue, thread per (b, n). yws layout [k*4096+n][b*12+t].
// ---------------------------------------------------------------------------
__global__ __launch_bounds__(64) void epilogue_kernel(
    const void* __restrict__ xv, const float* __restrict__ yws,
    const void* __restrict__ chebv, const void* __restrict__ gcnwv,
    const void* __restrict__ gcnbv, const void* __restrict__ g1wv,
    const void* __restrict__ g1bv, const void* __restrict__ g2wv,
    const void* __restrict__ g2bv,
    float* __restrict__ out, const int* __restrict__ flag)
{
    __shared__ float gwL[9216];   // [t][j*12+o]
    __shared__ float cwL[192];    // [j*3+k]
    __shared__ float w1L[216];    // [o*18 + c*3 + kh]  (kw=1 tap)
    __shared__ float w2L[216];
    __shared__ float wbL[36];

    const int tid = threadIdx.x;
    const int isf32 = flag[0];

    for (int i = tid; i < 9216; i += 64) {
        int o = i / 768, t = (i / 64) % 12, j = i % 64;   // gcn_w flat (o,t,0,j)
        gwL[t * 768 + j * 12 + o] = ldf(gcnwv, i, isf32);
    }
    for (int i = tid; i < 192; i += 64) cwL[i] = ldf(chebv, i, isf32);
    for (int i = tid; i < 216; i += 64) {
        w1L[i] = ldf(g1wv, (size_t)i * 3 + 1, isf32);
        w2L[i] = ldf(g2wv, (size_t)i * 3 + 1, isf32);
    }
    if (tid < 12) {
        wbL[tid]      = ldf(gcnbv, tid, isf32);
        wbL[12 + tid] = ldf(g1bv, tid, isf32);
        wbL[24 + tid] = ldf(g2bv, tid, isf32);
    }
    __syncthreads();

    const int g = blockIdx.x * 64 + tid;   // 0..32767
    const int b = g >> 12;
    const int n = g & (NNODES - 1);

    float y[36];                           // [k*12+t]
#pragma unroll
    for (int k = 0; k < 3; k++) {
        const float* yp = yws + ((size_t)(k * NNODES + n)) * NCOLS + b * 12;
        float4 q0 = *(const float4*)(yp);
        float4 q1 = *(const float4*)(yp + 4);
        float4 q2 = *(const float4*)(yp + 8);
        y[k*12+0]=q0.x; y[k*12+1]=q0.y; y[k*12+2] =q0.z; y[k*12+3] =q0.w;
        y[k*12+4]=q1.x; y[k*12+5]=q1.y; y[k*12+6] =q1.z; y[k*12+7] =q1.w;
        y[k*12+8]=q2.x; y[k*12+9]=q2.y; y[k*12+10]=q2.z; y[k*12+11]=q2.w;
    }

    // ---- cheb -> relu -> sgc ----
    float sg[12];
#pragma unroll
    for (int o = 0; o < 12; o++) sg[o] = wbL[o];
    for (int t = 0; t < 12; t++) {
        const float y0 = y[t], y1 = y[12 + t], y2 = y[24 + t];
        const float* gwt = gwL + t * 768;
#pragma unroll 4
        for (int j = 0; j < 64; j++) {
            float h = y0 * cwL[j * 3] + y1 * cwL[j * 3 + 1] + y2 * cwL[j * 3 + 2];
            h = fmaxf(h, 0.f);
#pragma unroll
            for (int o = 0; o < 12; o++) sg[o] += h * gwt[j * 12 + o];
        }
    }

    // ---- GLU (dilated conv: taps n-2, n, n+2; only kw=1 alive) ----
    float xa[18], xg[18];
#pragma unroll
    for (int c = 0; c < 6; c++)
#pragma unroll
        for (int kh = 0; kh < 3; kh++) {
            int m = n + 2 * kh - 2;
            bool ok = ((unsigned)m < (unsigned)NNODES);
            xa[c * 3 + kh] = ok ? ldf(xv, ((size_t)(b * 12 + c)) * NNODES + m, isf32) : 0.f;
            xg[c * 3 + kh] = ok ? ldf(xv, ((size_t)(b * 12 + c + 6)) * NNODES + m, isf32) : 0.f;
        }

#pragma unroll
    for (int o = 0; o < 12; o++) {
        float av = wbL[12 + o], gv = wbL[24 + o];
#pragma unroll
        for (int i = 0; i < 18; i++) {
            av += xa[i] * w1L[o * 18 + i];
            gv += xg[i] * w2L[o * 18 + i];
        }
        float s = 1.f / (1.f + expf(-gv));
        out[((size_t)(b * 12 + o)) * NNODES + n] = av * s + sg[o];
    }
}

// ---------------------------------------------------------------------------
// Fallback single kernel (only if ws too small): round-5 verified path.
// ---------------------------------------------------------------------------
__global__ __launch_bounds__(64) void fused_simple(
    const void* __restrict__ xv, const void* __restrict__ adjv,
    const void* __restrict__ chebv, const void* __restrict__ gcnwv,
    const void* __restrict__ gcnbv, const void* __restrict__ g1wv,
    const void* __restrict__ g1bv, const void* __restrict__ g2wv,
    const void* __restrict__ g2bv,
    float* __restrict__ out, const int* __restrict__ flag)
{
    __shared__ float gwL[9216];
    __shared__ float cwL[192];
    __shared__ float w1L[216];
    __shared__ float w2L[216];
    __shared__ float wbL[36];

    const int tid = threadIdx.x;
    const int isf32 = flag[0];

    for (int i = tid; i < 9216; i += 64) {
        int o = i / 768, t = (i / 64) % 12, j = i % 64;
        gwL[t * 768 + j * 12 + o] = ldf(gcnwv, i, isf32);
    }
    for (int i = tid; i < 192; i += 64) cwL[i] = ldf(chebv, i, isf32);
    for (int i = tid; i < 216; i += 64) {
        w1L[i] = ldf(g1wv, (size_t)i * 3 + 1, isf32);
        w2L[i] = ldf(g2wv, (size_t)i * 3 + 1, isf32);
    }
    if (tid < 12) {
        wbL[tid]      = ldf(gcnbv, tid, isf32);
        wbL[12 + tid] = ldf(g1bv, tid, isf32);
        wbL[24 + tid] = ldf(g2bv, tid, isf32);
    }
    __syncthreads();

    const int g = blockIdx.x * 64 + tid;
    const int b = g >> 12;
    const int n = g & (NNODES - 1);

    float y[3][12];
#pragma unroll
    for (int k = 0; k < 3; k++)
#pragma unroll
        for (int t = 0; t < 12; t++) y[k][t] = 0.f;

    for (int m0 = 0; m0 < NNODES; m0 += 8) {
        float a0[8], a1[8], a2[8];
        ld8(a0, adjv, ((size_t)(0 * NNODES + n)) * NNODES + m0, isf32);
        ld8(a1, adjv, ((size_t)(1 * NNODES + n)) * NNODES + m0, isf32);
        ld8(a2, adjv, ((size_t)(2 * NNODES + n)) * NNODES + m0, isf32);
#pragma unroll
        for (int t = 0; t < 12; t++) {
            float x8[8];
            ld8(x8, xv, ((size_t)(b * 12 + t)) * NNODES + m0, isf32);
#pragma unroll
            for (int j = 0; j < 8; j++) {
                y[0][t] += a0[j] * x8[j];
                y[1][t] += a1[j] * x8[j];
                y[2][t] += a2[j] * x8[j];
            }
        }
    }

    float sg[12];
#pragma unroll
    for (int o = 0; o < 12; o++) sg[o] = wbL[o];
    for (int t = 0; t < 12; t++) {
        const float y0 = y[0][t], y1 = y[1][t], y2 = y[2][t];
        const float* gwt = gwL + t * 768;
#pragma unroll 4
        for (int j = 0; j < 64; j++) {
            float h = y0 * cwL[j * 3] + y1 * cwL[j * 3 + 1] + y2 * cwL[j * 3 + 2];
            h = fmaxf(h, 0.f);
#pragma unroll
            for (int o = 0; o < 12; o++) sg[o] += h * gwt[j * 12 + o];
        }
    }

    float xa[18], xg[18];
#pragma unroll
    for (int c = 0; c < 6; c++)
#pragma unroll
        for (int kh = 0; kh < 3; kh++) {
            int m = n + 2 * kh - 2;
            bool ok = ((unsigned)m < (unsigned)NNODES);
            xa[c * 3 + kh] = ok ? ldf(xv, ((size_t)(b * 12 + c)) * NNODES + m, isf32) : 0.f;
            xg[c * 3 + kh] = ok ? ldf(xv, ((size_t)(b * 12 + c + 6)) * NNODES + m, isf32) : 0.f;
        }

#pragma unroll
    for (int o = 0; o < 12; o++) {
        float av = wbL[12 + o], gv = wbL[24 + o];
#pragma unroll
        for (int i = 0; i < 18; i++) {
            av += xa[i] * w1L[o * 18 + i];
            gv += xg[i] * w2L[o * 18 + i];
        }
        float s = 1.f / (1.f + expf(-gv));
        out[((size_t)(b * 12 + o)) * NNODES + n] = av * s + sg[o];
    }
}

// ---------------------------------------------------------------------------
extern "C" void kernel_launch(void* const* d_in, const int* in_sizes, int n_in,
                              void* d_out, int out_size, void* d_ws, size_t ws_size,
                              hipStream_t stream)
{
    int* flag = (int*)d_ws;                       // 64 B reserved
    float* yws = (float*)((char*)d_ws + 64);      // 12288*96 floats = 4.72 MB
    const size_t need = 64 + (size_t)NROWS * NCOLS * 4;

    hipLaunchKernelGGL(probe_dtype, dim3(1), dim3(64), 0, stream,
                       (const unsigned int*)d_in[1], flag);

    if (ws_size >= need) {
        hipLaunchKernelGGL(gemm_y, dim3(192), dim3(256), 0, stream,
                           d_in[1], d_in[0], yws, flag);
        hipLaunchKernelGGL(epilogue_kernel, dim3(512), dim3(64), 0, stream,
                           d_in[0], yws, d_in[2], d_in[3], d_in[4],
                           d_in[5], d_in[6], d_in[7], d_in[8],
                           (float*)d_out, flag);
    } else {
        hipLaunchKernelGGL(fused_simple, dim3(512), dim3(64), 0, stream,
                           d_in[0], d_in[1], d_in[2], d_in[3], d_in[4],
                           d_in[5], d_in[6], d_in[7], d_in[8],
                           (float*)d_out, flag);
    }
}